// Round 7
// baseline (226.971 us; speedup 1.0000x reference)
//
#include <hip/hip_runtime.h>
#include <math.h>

// Problem constants (B=1, LAYERS=33, HEADS=20, SEQ=512)
#define SEQ   512
#define NF    660
#define CROP  510
#define EOSI  2
#define RT    16           // rows per block (pass1)
#define GH    20           // heads per group (pass1)
#define NT_   32           // row tiles
#define NG    33           // head groups

typedef float f4 __attribute__((ext_vector_type(4)));
typedef float f2 __attribute__((ext_vector_type(2)));

// barrier that waits only LDS ops -- keeps global-load prefetch in flight
#define BARRIER_LGKM() asm volatile("s_waitcnt lgkmcnt(0)\n\ts_barrier" ::: "memory")

// load 4 rows (8 x f4) of head f at rows row0..row0+3
#define LOADP8(buf, f) do {                                                   \
    const float* _b = A + ((size_t)(f) << 18) + ((size_t)row0 << 9);          \
    buf[0] = *(const f4*)(_b + 4 * lane);                                     \
    buf[1] = *(const f4*)(_b + 256 + 4 * lane);                               \
    buf[2] = *(const f4*)(_b + 512 + 4 * lane);                               \
    buf[3] = *(const f4*)(_b + 768 + 4 * lane);                               \
    buf[4] = *(const f4*)(_b + 1024 + 4 * lane);                              \
    buf[5] = *(const f4*)(_b + 1280 + 4 * lane);                              \
    buf[6] = *(const f4*)(_b + 1536 + 4 * lane);                              \
    buf[7] = *(const f4*)(_b + 1792 + 4 * lane);                              \
} while (0)

// consume 4 rows of head h; row sums -> LDS rowstage (no global store)
#define COMP8(buf, wf, cacc, h) do {                                          \
    _Pragma("unroll")                                                         \
    for (int rr = 0; rr < 4; ++rr) {                                          \
        const float mi = mrow[rr];                                            \
        f4 x0 = buf[2 * rr], x1 = buf[2 * rr + 1];                            \
        float vals[8] = {x0[0], x0[1], x0[2], x0[3],                          \
                         x1[0], x1[1], x1[2], x1[3]};                         \
        float rs = 0.f;                                                       \
        _Pragma("unroll")                                                     \
        for (int e = 0; e < 8; ++e) {                                         \
            const float v = vals[e];                                          \
            wa_acc[rr][e] += (wf) * v;                                        \
            rs += mskv[e] * v;                                                \
            cacc[e] += mi * v;                                                \
        }                                                                     \
        _Pragma("unroll")                                                     \
        for (int off = 32; off > 0; off >>= 1)                                \
            rs += __shfl_down(rs, off, 64);                                   \
        if (lane == 0) rowstage[h][wave * 4 + rr] = rs;                       \
    }                                                                         \
} while (0)

// flush colstage group q (heads fbase+4q .. +3) -> colpart (2048 contiguous floats)
#define FLUSHCOL(q) do {                                                      \
    float* __restrict__ _dst = colpart + ((size_t)t * NF + fbase + 4 * (q)) * SEQ; \
    const float* __restrict__ _src = &colstage[(q) & 1][0][0];                \
    *(f4*)(_dst + 4 * tid)        = *(const f4*)(_src + 4 * tid);             \
    *(f4*)(_dst + 1024 + 4 * tid) = *(const f4*)(_src + 1024 + 4 * tid);      \
} while (0)

// cross-wave col combine for head h; flush of the PREVIOUS 4-head group happens
// right after the barrier (all its writes are barrier-crossed; the [2] double
// buffer on colstage keeps flush-reads and this head's writes disjoint)
#define COMBINE(cacc, h) do {                                                 \
    const int pp = (h) & 1;                                                   \
    _Pragma("unroll")                                                         \
    for (int e = 0; e < 8; ++e)                                               \
        col_lds[pp][wave][(e >> 2) * 256 + 4 * lane + (e & 3)] = cacc[e];     \
    BARRIER_LGKM();                                                           \
    if (((h) & 3) == 0 && (h) > 0) FLUSHCOL((h) / 4 - 1);                     \
    {                                                                         \
        const int c = 2 * tid;                                                \
        f2 s;                                                                 \
        s[0] = col_lds[pp][0][c]     + col_lds[pp][1][c]                      \
             + col_lds[pp][2][c]     + col_lds[pp][3][c];                     \
        s[1] = col_lds[pp][0][c + 1] + col_lds[pp][1][c + 1]                  \
             + col_lds[pp][2][c + 1] + col_lds[pp][3][c + 1];                 \
        *(f2*)&colstage[((h) >> 2) & 1][(h) & 3][c] = s;                      \
    }                                                                         \
} while (0)

// ---------------- Pass 1: stream 692MB once ----------------
// grid (32 row-tiles, 33 head-groups), block 256 (4 waves).
// 35.25 KB LDS; launch_bounds(256,3) -> 12 waves/CU; steady 8 KB/wave in flight.
__global__ __launch_bounds__(256, 3) void pass1_kernel(
    const float* __restrict__ A, const int* __restrict__ tokens,
    const float* __restrict__ weight,
    float* __restrict__ WApart, float* __restrict__ rowsum, float* __restrict__ colpart)
{
    __shared__ float msk[SEQ];                // 2 KB
    __shared__ float col_lds[2][4][SEQ];      // 16 KB per-head ping-pong
    __shared__ float colstage[2][4][SEQ];     // 16 KB double-buffered 4-head groups
    __shared__ float rowstage[GH][RT];        // 1.25 KB

    const int t = blockIdx.x, g = blockIdx.y;
    const int tid = threadIdx.x, wave = tid >> 6, lane = tid & 63;
    const int fbase = g * GH;

    for (int j = tid; j < SEQ; j += 256)
        msk[j] = (j >= 1 && j <= SEQ - 2 && tokens[j] != EOSI) ? 1.f : 0.f;
    BARRIER_LGKM();

    float mskv[8];
    #pragma unroll
    for (int e = 0; e < 8; ++e)
        mskv[e] = msk[(e >> 2) * 256 + 4 * lane + (e & 3)];

    const int row0 = t * RT + wave * 4;
    const float mrow[4] = {msk[row0], msk[row0 + 1], msk[row0 + 2], msk[row0 + 3]};

    float wa_acc[4][8];
    #pragma unroll
    for (int r = 0; r < 4; ++r)
        #pragma unroll
        for (int e = 0; e < 8; ++e) wa_acc[r][e] = 0.f;

    f4 bufA[8], bufB[8];
    LOADP8(bufA, fbase);                      // prime

    #pragma unroll 1
    for (int hh = 0; hh < 10; ++hh) {
        const int h0 = 2 * hh, h1 = h0 + 1;

        float cacc0[8] = {0, 0, 0, 0, 0, 0, 0, 0};
        LOADP8(bufB, fbase + h1);             // next head in flight during COMP(bufA)
        COMP8(bufA, weight[fbase + h0], cacc0, h0);
        COMBINE(cacc0, h0);

        float cacc1[8] = {0, 0, 0, 0, 0, 0, 0, 0};
        if (hh < 9) LOADP8(bufA, fbase + h0 + 2);
        COMP8(bufB, weight[fbase + h1], cacc1, h1);
        COMBINE(cacc1, h1);
    }

    BARRIER_LGKM();   // colstage group 4 + rowstage complete

    FLUSHCOL(4);      // heads 16..19

    // ---- flush rowstage -> rowsum (16 consecutive floats per head)
    #pragma unroll
    for (int it = 0; it < 2; ++it) {
        const int e = it * 256 + tid;
        if (e < GH * RT) {
            const int h = e >> 4, r = e & 15;
            rowsum[((size_t)(fbase + h) << 9) + t * RT + r] = rowstage[h][r];
        }
    }
    // ---- flush WApart (write-once, float4 coalesced)
    float* __restrict__ wp = WApart + (size_t)g * SEQ * SEQ;
    #pragma unroll
    for (int rr = 0; rr < 4; ++rr) {
        f4 o0 = {wa_acc[rr][0], wa_acc[rr][1], wa_acc[rr][2], wa_acc[rr][3]};
        f4 o1 = {wa_acc[rr][4], wa_acc[rr][5], wa_acc[rr][6], wa_acc[rr][7]};
        *(f4*)(wp + ((size_t)(row0 + rr) << 9) + 4 * lane) = o0;
        *(f4*)(wp + ((size_t)(row0 + rr) << 9) + 256 + 4 * lane) = o1;
    }
}

// ---------------- Kernel 2 (merged): WA-reduce + per-head a1/a12/scale --------
__global__ __launch_bounds__(512) void kernel2(
    const float* __restrict__ WApart, float* __restrict__ WA,
    const float* __restrict__ rowsum, const float* __restrict__ colpart,
    const int* __restrict__ tokens, const float* __restrict__ weight,
    float* __restrict__ a1, float* __restrict__ sfac)
{
    __shared__ float part[8];
    const int b = blockIdx.x, tid = threadIdx.x;
    if (b < 128) {
        const size_t idx4 = (size_t)b * 512 + tid;     // float4 index, 65536 total
        f4 a = *(const f4*)(WApart + 4 * idx4);
        #pragma unroll 8
        for (int g = 1; g < NG; ++g) {
            f4 x = *(const f4*)(WApart + (size_t)g * (SEQ * SEQ) + 4 * idx4);
            a += x;
        }
        *(f4*)(WA + 4 * idx4) = a;
    } else {
        const int f = b - 128, j = tid;
        float cs = 0.f;
        #pragma unroll 8
        for (int t = 0; t < NT_; ++t)
            cs += colpart[((size_t)t * NF + f) * SEQ + j];
        const float m = (j >= 1 && j <= SEQ - 2 && tokens[j] != EOSI) ? 1.f : 0.f;
        const float v = m * (rowsum[((size_t)f << 9) + j] + cs);
        a1[((size_t)f << 9) + j] = v;
        float s = v;
        #pragma unroll
        for (int off = 32; off > 0; off >>= 1)
            s += __shfl_down(s, off, 64);
        const int wave = tid >> 6, lane = tid & 63;
        if (lane == 0) part[wave] = s;
        __syncthreads();
        if (tid == 0) {
            float a12 = 0.f;
            #pragma unroll
            for (int k = 0; k < 8; ++k) a12 += part[k];
            sfac[f] = weight[f] / a12;
        }
    }
}

// ---------------- Pass 3: rank-660 outer-product + WA + sigmoid ----------------
// grid (32,32) = 1024 blocks; 16x16 output tile, 1 output/thread; 32-f chunks
__global__ __launch_bounds__(256) void pass3_kernel(
    const float* __restrict__ WA, const float* __restrict__ a1,
    const float* __restrict__ sfac, const int* __restrict__ tokens,
    const float* __restrict__ bias, float* __restrict__ out)
{
    const int TI = blockIdx.y * 16;
    const int TJ = blockIdx.x * 16;
    const int tid = threadIdx.x;
    const int tx = tid & 15, ty = tid >> 4;

    __shared__ float u_s[32][17];
    __shared__ float v_s[32][17];

    float acc = 0.f;

    for (int f0 = 0; f0 < NF; f0 += 32) {
        #pragma unroll
        for (int c = 0; c < 4; ++c) {
            const int e = c * 256 + tid;        // 0..1023
            const int arr = e >> 9, ff = (e >> 4) & 31, ii = e & 15;
            const int f = f0 + ff;
            float val = 0.f;
            if (f < NF) {
                if (arr == 0) {
                    int Iu = TI + 1 + ii; if (Iu > SEQ - 1) Iu = SEQ - 1;
                    val = a1[((size_t)f << 9) + Iu] * sfac[f];
                } else {
                    int Ju = TJ + 1 + ii; if (Ju > SEQ - 1) Ju = SEQ - 1;
                    val = a1[((size_t)f << 9) + Ju];
                }
            }
            if (arr == 0) u_s[ff][ii] = val; else v_s[ff][ii] = val;
        }
        __syncthreads();
        #pragma unroll
        for (int ff = 0; ff < 32; ++ff)
            acc += u_s[ff][ty] * v_s[ff][tx];
        __syncthreads();
    }

    const int i = TI + ty, j = TJ + tx;
    if (i < CROP && j < CROP) {
        const int I = i + 1, J = j + 1;
        const float mi = (tokens[I] != EOSI) ? 1.f : 0.f;
        const float mj = (tokens[J] != EOSI) ? 1.f : 0.f;
        const float first = mi * mj * (WA[((size_t)I << 9) + J] + WA[((size_t)J << 9) + I]);
        const float logit = first - acc + bias[0];
        out[(size_t)i * CROP + j] = 1.f / (1.f + expf(-logit));
    }
}

extern "C" void kernel_launch(void* const* d_in, const int* in_sizes, int n_in,
                              void* d_out, int out_size, void* d_ws, size_t ws_size,
                              hipStream_t stream) {
    const int*   tokens = (const int*)d_in[0];
    const float* A      = (const float*)d_in[1];
    const float* weight = (const float*)d_in[2];
    const float* bias   = (const float*)d_in[3];
    float* out = (float*)d_out;

    // workspace (floats), all write-once, no zeroing:
    // WApart[33*512*512] | colpart[32*660*512] | WA[512*512] | rowsum[660*512] | a1[660*512] | sfac[660]
    float* WApart  = (float*)d_ws;
    float* colpart = WApart + (size_t)NG * SEQ * SEQ;
    float* WA      = colpart + (size_t)NT_ * NF * SEQ;
    float* rowsum  = WA + (size_t)SEQ * SEQ;
    float* a1      = rowsum + (size_t)NF * SEQ;
    float* sfac    = a1 + (size_t)NF * SEQ;

    dim3 g1(NT_, NG);   // 32 x 33
    pass1_kernel<<<g1, 256, 0, stream>>>(A, tokens, weight, WApart, rowsum, colpart);

    kernel2<<<128 + NF, 512, 0, stream>>>(WApart, WA, rowsum, colpart, tokens, weight, a1, sfac);

    dim3 g3(32, 32);
    pass3_kernel<<<g3, 256, 0, stream>>>(WA, a1, sfac, tokens, bias, out);
}